// Round 4
// baseline (189.101 us; speedup 1.0000x reference)
//
#include <hip/hip_runtime.h>
#include <math.h>

#define EPS32 1.1920929e-07f

constexpr int B = 16, C = 80, H = 128, W = 128, NBOX = 64;
constexpr int NCORR = B * NBOX;        // 1024 correction-carrying blocks
constexpr int NBLK  = 2048;            // all blocks stream; 8 blocks/CU, one round
constexpr int NTOT  = B * C * H * W;   // 20,971,520
constexpr int NV4   = NTOT / 4;        // 5,242,880 float4s
constexpr int SSTRIDE = NBLK * 256;    // 524,288 -> exactly 10 float4 iters/thread
constexpr int SITER = NV4 / SSTRIDE;   // 10
static_assert(SITER * SSTRIDE == NV4, "streaming must tile exactly");

// Two-level completion ticket. R3 lesson (re-confirming the prior session's
// journal): 2048 device-scope atomics on ONE line serialize at ~45 ns each
// (~92 us, line ping-pongs across 8 XCDs). Split: 32 level-1 counters on
// separate 128 B lines (<=64 increments each, staggered), then one level-2
// line touched by only 32 blocks. Worst serial tail ~1-2 us.
constexpr int NGRP = 32;               // level-1 groups (k & 31)
constexpr int GRPSZ = NBLK / NGRP;     // 64 blocks per group
constexpr int LINE_U32 = 32;           // 128 B line stride in uints

__device__ __forceinline__ float f0_term(float p) {
    // ct == 0 branch of the focal loss: -log(1-p+1e-12) * p^2
    return -__logf(1.0f - p + 1e-12f) * p * p;
}

// Block-wide sum; result valid on thread 0 only. Contains one __syncthreads.
__device__ __forceinline__ float block_reduce_add(float v, float* sred) {
    #pragma unroll
    for (int off = 32; off > 0; off >>= 1)
        v += __shfl_down(v, off, 64);
    int lane = threadIdx.x & 63;
    int wid  = threadIdx.x >> 6;
    if (lane == 0) sred[wid] = v;
    __syncthreads();
    if (threadIdx.x == 0) {
        float s = sred[0];
        #pragma unroll
        for (int i = 1; i < 4; ++i) s += sred[i];
        return s;
    }
    return 0.0f;
}

// Single kernel. Each block writes one float4 partial {center, wh, offset, af}
// to ws4[blockIdx.x]; the LAST block (two-level ticket) folds the 32 KB
// finalize reduction in-kernel, eliminating the second launch + gap.
// Blocks 0..NCORR-1 additionally own box (b = k>>6, n = k&63)'s sparse correction.
__global__ __launch_bounds__(256) void fused_kernel(
    const float* __restrict__ cp, const float* __restrict__ whp,
    const float* __restrict__ ofp, const float* __restrict__ boxes,
    const int* __restrict__ labels, float4* __restrict__ ws4,
    unsigned int* __restrict__ tickets, float* __restrict__ out)
{
    __shared__ float sred[4];
    __shared__ int   scx[NBOX], scy[NBOX], sre[NBOX], slab[NBOX];
    __shared__ float sinv[NBOX];
    __shared__ unsigned long long cand_mask;   // same-batch same-label boxes
    __shared__ float s_woa[3];                 // {wh, offset, af} from thread n
    __shared__ unsigned int s_islast;
    const int t = threadIdx.x;
    const int k = blockIdx.x;
    const bool has_box = (k < NCORR);
    const int b = (k >> 6) & (B - 1);
    const int n = k & 63;

    if (has_box) {
        // ---------- box setup (wave 0) ----------
        if (t < NBOX) {
            const float* bx = boxes + ((b * NBOX + t) << 2);
            float x1 = bx[0], y1 = bx[1], x2 = bx[2], y2 = bx[3];
            // w_ratio = h_ratio = 128/512 = 0.25 (exact power-of-2 scalings)
            float cx = (x1 + x2) * 0.25f * 0.5f;
            float cy = (y1 + y2) * 0.25f * 0.5f;
            int cxi = (int)floorf(cx);
            int cyi = (int)floorf(cy);
            float sw = (x2 - x1) * 0.25f;
            float sh = (y2 - y1) * 0.25f;
            // gaussian radius, min_overlap = 0.3 (h = sh, w = sw)
            float h = sh, w = sw;
            float b1 = h + w;
            float c1 = w * h * 0.7f / 1.3f;
            float r1 = (b1 - sqrtf(b1 * b1 - 4.0f * c1)) * 0.5f;
            float b2 = 2.0f * (h + w);
            float c2 = 0.7f * w * h;
            float r2 = (b2 - sqrtf(b2 * b2 - 16.0f * c2)) * 0.125f;
            float b3 = -0.6f * (h + w);
            float c3 = -0.7f * w * h;
            float r3 = (b3 + sqrtf(b3 * b3 - 4.8f * c3)) / 2.4f;
            float r = fminf(fminf(r1, r2), r3);
            int rad = (int)fmaxf(0.0f, floorf(r));
            float d = (float)(2 * rad + 1);
            float sigma2 = 2.0f * d / 6.0f * (d / 6.0f);
            scx[t] = cxi; scy[t] = cyi;
            sre[t] = rad < 16 ? rad : 16;     // window clamp (reference grid is +-16)
            slab[t] = labels[b * NBOX + t];
            sinv[t] = 1.0f / sigma2;
            if (t == 0) { s_woa[0] = 0.0f; s_woa[1] = 0.0f; s_woa[2] = 0.0f; }
            // keep per-thread box values for the t==n writes below
            float ox = cx - (float)cxi, oy = cy - (float)cyi;
            __syncthreads();
            // ---------- wave-0 ballots replace serial thread-0 loops ----------
            const int cxn = scx[n], cyn = scy[n], labn = slab[n];
            bool same_cell = (scx[t] == cxn) && (scy[t] == cyn);
            // wh/offset scatter-set => last write (max index) wins per (cyi,cxi)
            unsigned long long clash = __ballot(same_cell && (t > n));
            // af counts distinct (label, cyi, cxi) => first occurrence
            unsigned long long firstm = __ballot(same_cell && (slab[t] == labn) && (t < n));
            // candidate set for the gaussian max: same-batch same-label boxes
            unsigned long long cand = __ballot(slab[t] == labn);
            if (t == n) {
                cand_mask = cand;
                if (clash == 0ULL) {
                    int i0 = ((b * 2 + 0) * H + cyn) * W + cxn;
                    int i1 = ((b * 2 + 1) * H + cyn) * W + cxn;
                    s_woa[0] = fabsf(whp[i0] - sw) + fabsf(whp[i1] - sh);
                    s_woa[1] = fabsf(ofp[i0] - ox) + fabsf(ofp[i1] - oy);
                }
                if (firstm == 0ULL) s_woa[2] = 1.0f;
            }
        } else {
            __syncthreads();   // matches the wave-0 barrier above
        }
    }

    // ---------- dense streaming slice (all blocks): 10 float4s/thread ----------
    const float4* cp4 = (const float4*)cp;
    const int base = k * 256 + t;
    float s0 = 0.0f, s1 = 0.0f;
    #pragma unroll 1
    for (int j = 0; j < SITER; j += 2) {
        float4 a  = cp4[base + (j + 0) * SSTRIDE];
        float4 bb = cp4[base + (j + 1) * SSTRIDE];
        s0 += f0_term(a.x) + f0_term(a.y) + f0_term(a.z) + f0_term(a.w);
        s1 += f0_term(bb.x) + f0_term(bb.y) + f0_term(bb.z) + f0_term(bb.w);
    }
    float center = s0 + s1;

    if (has_box) {
        __syncthreads();   // cand_mask / box LDS visible to all 4 waves

        // ---------- sparse correction: this block's box window ----------
        const int c   = slab[n];
        const int R   = sre[n];
        const int Wd  = 2 * R + 1;
        const int cells = Wd * Wd;
        const int cx0 = scx[n], cy0 = scy[n];
        const unsigned long long cmask = cand_mask;
        float corr = 0.0f;
        for (int cell = t; cell < cells; cell += 256) {
            int dy = cell / Wd - R;
            int dx = cell - (dy + R) * Wd - R;
            int y = cy0 + dy, x = cx0 + dx;
            if ((unsigned)y >= (unsigned)H || (unsigned)x >= (unsigned)W) continue;
            // ct = max gaussian over covering same-label boxes; owner = min index
            int minm = NBOX;
            float ct = 0.0f;
            unsigned long long mm = cmask;
            while (mm) {
                int m = __ffsll(mm) - 1;
                mm &= mm - 1;
                int ddx = x - scx[m], ddy = y - scy[m];
                int re = sre[m];
                if (ddx > re || ddx < -re || ddy > re || ddy < -re) continue;
                if (m < minm) minm = m;
                float d2 = (float)(ddx * ddx + ddy * ddy);
                float kv = (d2 == 0.0f) ? 1.0f : __expf(-d2 * sinv[m]);
                if (kv < EPS32) kv = 0.0f;          // reference EPS cut
                ct = fmaxf(ct, kv);
            }
            if (minm == n) {                         // this block owns the cell
                float p = cp[((b * C + c) * H + y) * W + x];
                float lt = __logf(1.0f - p + 1e-12f);
                float omc = 1.0f - ct;
                float w2 = omc * omc;
                float w4 = w2 * w2;
                // f(p,ct) - f0(p): neg-weight delta + pos term at exact centers
                float val = -lt * p * p * (w4 - 1.0f);
                if (ct == 1.0f) {
                    float q = 1.0f - p;
                    val += -__logf(p + 1e-12f) * q * q;
                }
                corr += val;
            }
        }
        center += corr;
    }

    float cs = block_reduce_add(center, sred);   // contains a __syncthreads

    // ---------- publish partial + two-level last-block ticket ----------
    if (t == 0) {
        float4 o;
        o.x = cs;
        if (has_box) { o.y = s_woa[0]; o.z = s_woa[1]; o.w = s_woa[2]; }
        else         { o.y = 0.0f;     o.z = 0.0f;     o.w = 0.0f;     }
        ws4[k] = o;
        __threadfence();                          // release partial before ticket
        unsigned int last = 0u;
        unsigned int g = (unsigned)(k & (NGRP - 1));      // co-finishers spread lines
        unsigned int p1 = atomicAdd(&tickets[g * LINE_U32], 1u);
        if (p1 == (unsigned)(GRPSZ - 1)) {                // last in group (of 64)
            unsigned int p2 = atomicAdd(&tickets[NGRP * LINE_U32], 1u);
            last = (p2 == (unsigned)(NGRP - 1));          // last of 32 groups
        }
        s_islast = last;
    }
    __syncthreads();

    if (s_islast) {
        // ---------- in-kernel finalize (last block only) ----------
        __threadfence();                          // acquire: see all partials
        float c = 0.0f, wh = 0.0f, of = 0.0f, af = 0.0f;
        for (int i = t; i < NBLK; i += 256) {
            float4 v = ws4[i];
            c += v.x; wh += v.y; of += v.z; af += v.w;
        }
        float fc = block_reduce_add(c, sred);  __syncthreads();
        float fw = block_reduce_add(wh, sred); __syncthreads();
        float fo = block_reduce_add(of, sred); __syncthreads();
        float fa = block_reduce_add(af, sred);
        if (t == 0) {
            float a = fmaxf(1.0f, fa);
            out[0] = fc / (a + EPS32)
                   + 0.1f * fw / (a * 2.0f + EPS32)
                   + fo / (a * 2.0f + EPS32);
        }
    }
}

extern "C" void kernel_launch(void* const* d_in, const int* in_sizes, int n_in,
                              void* d_out, int out_size, void* d_ws, size_t ws_size,
                              hipStream_t stream) {
    const float* cp     = (const float*)d_in[0];   // center_pred (16,80,128,128)
    const float* whp    = (const float*)d_in[1];   // wh_pred     (16,2,128,128)
    const float* ofp    = (const float*)d_in[2];   // offset_pred (16,2,128,128)
    const float* boxes  = (const float*)d_in[3];   // (16,64,4)
    const int*   labels = (const int*)d_in[4];     // (16,64)
    float4* ws4 = (float4*)d_ws;                   // NBLK float4 partials (32 KB)
    unsigned int* tickets = (unsigned int*)((char*)d_ws + NBLK * sizeof(float4));

    // Workspace is re-poisoned each iteration -> tickets MUST be zeroed.
    // One stream-ordered memset over the 33 counter lines (4.2 KB), ~1 us.
    hipMemsetAsync(tickets, 0, (NGRP + 1) * LINE_U32 * sizeof(unsigned int), stream);
    fused_kernel<<<NBLK, 256, 0, stream>>>(cp, whp, ofp, boxes, labels, ws4,
                                           tickets, (float*)d_out);
}

// Round 5
// 134.855 us; speedup vs baseline: 1.4023x; 1.4023x over previous
//
#include <hip/hip_runtime.h>
#include <math.h>

#define EPS32 1.1920929e-07f

constexpr int B = 16, C = 80, H = 128, W = 128, NBOX = 64;
constexpr int NCORR = B * NBOX;        // 1024 correction-carrying blocks
constexpr int NBLK  = 2048;            // all blocks stream; 8 blocks/CU, one round
constexpr int NTOT  = B * C * H * W;   // 20,971,520
constexpr int NV4   = NTOT / 4;        // 5,242,880 float4s
constexpr int SSTRIDE = NBLK * 256;    // 524,288 -> exactly 10 float4 iters/thread
constexpr int SITER = NV4 / SSTRIDE;   // 10
static_assert(SITER * SSTRIDE == NV4, "streaming must tile exactly");

// R3/R4 lesson: per-block __threadfence() (agent-scope release) lowers to
// buffer_wbl2 sc1 — an L2 WRITEBACK per block. 2048 of them serialized the
// kernel at ~92 us REGARDLESS of atomic line spreading (R4: 33 lines, same
// 92 us => the fence, not line contention, was the cost). This version has
// ZERO fences: partials are published with sc0/sc1 write-through atomic
// stores (coherent point), ordered before the ticket by s_waitcnt vmcnt(0),
// and read back by the winner with sc1 read-through atomic loads.
constexpr int NGRP = 32;               // level-1 ticket groups (k & 31)
constexpr int GRPSZ = NBLK / NGRP;     // 64 blocks per group
constexpr int LINE_U32 = 32;           // 128 B line stride in uints

__device__ __forceinline__ float f0_term(float p) {
    // ct == 0 branch of the focal loss: -log(1-p+1e-12) * p^2
    return -__logf(1.0f - p + 1e-12f) * p * p;
}

// Block-wide sum; result valid on thread 0 only. Contains one __syncthreads.
__device__ __forceinline__ float block_reduce_add(float v, float* sred) {
    #pragma unroll
    for (int off = 32; off > 0; off >>= 1)
        v += __shfl_down(v, off, 64);
    int lane = threadIdx.x & 63;
    int wid  = threadIdx.x >> 6;
    if (lane == 0) sred[wid] = v;
    __syncthreads();
    if (threadIdx.x == 0) {
        float s = sred[0];
        #pragma unroll
        for (int i = 1; i < 4; ++i) s += sred[i];
        return s;
    }
    return 0.0f;
}

// Single kernel. Each block publishes one {center, wh, offset, af} partial to
// ws[4k..4k+3] via device-coherent stores; the LAST block (two-level ticket)
// folds the finalize reduction in-kernel (no second launch, no fences).
// Blocks 0..NCORR-1 additionally own box (b = k>>6, n = k&63)'s sparse correction.
__global__ __launch_bounds__(256) void fused_kernel(
    const float* __restrict__ cp, const float* __restrict__ whp,
    const float* __restrict__ ofp, const float* __restrict__ boxes,
    const int* __restrict__ labels, float* __restrict__ ws,
    unsigned int* __restrict__ tickets, float* __restrict__ out)
{
    __shared__ float sred[4];
    __shared__ int   scx[NBOX], scy[NBOX], sre[NBOX], slab[NBOX];
    __shared__ float sinv[NBOX];
    __shared__ unsigned long long cand_mask;   // same-batch same-label boxes
    __shared__ float s_woa[3];                 // {wh, offset, af} from thread n
    __shared__ unsigned int s_islast;
    const int t = threadIdx.x;
    const int k = blockIdx.x;
    const bool has_box = (k < NCORR);
    const int b = (k >> 6) & (B - 1);
    const int n = k & 63;

    if (has_box) {
        // ---------- box setup (wave 0) ----------
        if (t < NBOX) {
            const float* bx = boxes + ((b * NBOX + t) << 2);
            float x1 = bx[0], y1 = bx[1], x2 = bx[2], y2 = bx[3];
            // w_ratio = h_ratio = 128/512 = 0.25 (exact power-of-2 scalings)
            float cx = (x1 + x2) * 0.25f * 0.5f;
            float cy = (y1 + y2) * 0.25f * 0.5f;
            int cxi = (int)floorf(cx);
            int cyi = (int)floorf(cy);
            float sw = (x2 - x1) * 0.25f;
            float sh = (y2 - y1) * 0.25f;
            // gaussian radius, min_overlap = 0.3 (h = sh, w = sw)
            float h = sh, w = sw;
            float b1 = h + w;
            float c1 = w * h * 0.7f / 1.3f;
            float r1 = (b1 - sqrtf(b1 * b1 - 4.0f * c1)) * 0.5f;
            float b2 = 2.0f * (h + w);
            float c2 = 0.7f * w * h;
            float r2 = (b2 - sqrtf(b2 * b2 - 16.0f * c2)) * 0.125f;
            float b3 = -0.6f * (h + w);
            float c3 = -0.7f * w * h;
            float r3 = (b3 + sqrtf(b3 * b3 - 4.8f * c3)) / 2.4f;
            float r = fminf(fminf(r1, r2), r3);
            int rad = (int)fmaxf(0.0f, floorf(r));
            float d = (float)(2 * rad + 1);
            float sigma2 = 2.0f * d / 6.0f * (d / 6.0f);
            scx[t] = cxi; scy[t] = cyi;
            sre[t] = rad < 16 ? rad : 16;     // window clamp (reference grid is +-16)
            slab[t] = labels[b * NBOX + t];
            sinv[t] = 1.0f / sigma2;
            if (t == 0) { s_woa[0] = 0.0f; s_woa[1] = 0.0f; s_woa[2] = 0.0f; }
            // keep per-thread box values for the t==n writes below
            float ox = cx - (float)cxi, oy = cy - (float)cyi;
            __syncthreads();
            // ---------- wave-0 ballots replace serial thread-0 loops ----------
            const int cxn = scx[n], cyn = scy[n], labn = slab[n];
            bool same_cell = (scx[t] == cxn) && (scy[t] == cyn);
            // wh/offset scatter-set => last write (max index) wins per (cyi,cxi)
            unsigned long long clash = __ballot(same_cell && (t > n));
            // af counts distinct (label, cyi, cxi) => first occurrence
            unsigned long long firstm = __ballot(same_cell && (slab[t] == labn) && (t < n));
            // candidate set for the gaussian max: same-batch same-label boxes
            unsigned long long cand = __ballot(slab[t] == labn);
            if (t == n) {
                cand_mask = cand;
                if (clash == 0ULL) {
                    int i0 = ((b * 2 + 0) * H + cyn) * W + cxn;
                    int i1 = ((b * 2 + 1) * H + cyn) * W + cxn;
                    s_woa[0] = fabsf(whp[i0] - sw) + fabsf(whp[i1] - sh);
                    s_woa[1] = fabsf(ofp[i0] - ox) + fabsf(ofp[i1] - oy);
                }
                if (firstm == 0ULL) s_woa[2] = 1.0f;
            }
        } else {
            __syncthreads();   // matches the wave-0 barrier above
        }
    }

    // ---------- dense streaming slice (all blocks): 10 float4s/thread ----------
    const float4* cp4 = (const float4*)cp;
    const int base = k * 256 + t;
    float s0 = 0.0f, s1 = 0.0f;
    #pragma unroll 1
    for (int j = 0; j < SITER; j += 2) {
        float4 a  = cp4[base + (j + 0) * SSTRIDE];
        float4 bb = cp4[base + (j + 1) * SSTRIDE];
        s0 += f0_term(a.x) + f0_term(a.y) + f0_term(a.z) + f0_term(a.w);
        s1 += f0_term(bb.x) + f0_term(bb.y) + f0_term(bb.z) + f0_term(bb.w);
    }
    float center = s0 + s1;

    if (has_box) {
        __syncthreads();   // cand_mask / box LDS visible to all 4 waves

        // ---------- sparse correction: this block's box window ----------
        const int c   = slab[n];
        const int R   = sre[n];
        const int Wd  = 2 * R + 1;
        const int cells = Wd * Wd;
        const int cx0 = scx[n], cy0 = scy[n];
        const unsigned long long cmask = cand_mask;
        float corr = 0.0f;
        for (int cell = t; cell < cells; cell += 256) {
            int dy = cell / Wd - R;
            int dx = cell - (dy + R) * Wd - R;
            int y = cy0 + dy, x = cx0 + dx;
            if ((unsigned)y >= (unsigned)H || (unsigned)x >= (unsigned)W) continue;
            // ct = max gaussian over covering same-label boxes; owner = min index
            int minm = NBOX;
            float ct = 0.0f;
            unsigned long long mm = cmask;
            while (mm) {
                int m = __ffsll(mm) - 1;
                mm &= mm - 1;
                int ddx = x - scx[m], ddy = y - scy[m];
                int re = sre[m];
                if (ddx > re || ddx < -re || ddy > re || ddy < -re) continue;
                if (m < minm) minm = m;
                float d2 = (float)(ddx * ddx + ddy * ddy);
                float kv = (d2 == 0.0f) ? 1.0f : __expf(-d2 * sinv[m]);
                if (kv < EPS32) kv = 0.0f;          // reference EPS cut
                ct = fmaxf(ct, kv);
            }
            if (minm == n) {                         // this block owns the cell
                float p = cp[((b * C + c) * H + y) * W + x];
                float lt = __logf(1.0f - p + 1e-12f);
                float omc = 1.0f - ct;
                float w2 = omc * omc;
                float w4 = w2 * w2;
                // f(p,ct) - f0(p): neg-weight delta + pos term at exact centers
                float val = -lt * p * p * (w4 - 1.0f);
                if (ct == 1.0f) {
                    float q = 1.0f - p;
                    val += -__logf(p + 1e-12f) * q * q;
                }
                corr += val;
            }
        }
        center += corr;
    }

    float cs = block_reduce_add(center, sred);   // contains a __syncthreads

    // ---------- publish partial (coherent stores) + two-level ticket ----------
    if (t == 0) {
        float p0 = cs, p1 = 0.0f, p2 = 0.0f, p3 = 0.0f;
        if (has_box) { p1 = s_woa[0]; p2 = s_woa[1]; p3 = s_woa[2]; }
        float* wp = ws + 4 * k;
        // sc0/sc1 write-through stores: land at the coherent point, no L2 flush
        __hip_atomic_store(wp + 0, p0, __ATOMIC_RELAXED, __HIP_MEMORY_SCOPE_AGENT);
        __hip_atomic_store(wp + 1, p1, __ATOMIC_RELAXED, __HIP_MEMORY_SCOPE_AGENT);
        __hip_atomic_store(wp + 2, p2, __ATOMIC_RELAXED, __HIP_MEMORY_SCOPE_AGENT);
        __hip_atomic_store(wp + 3, p3, __ATOMIC_RELAXED, __HIP_MEMORY_SCOPE_AGENT);
        // order: partial stores complete (at coherent point) BEFORE the ticket.
        // This is a wave-local wait, NOT a cache flush (the R3/R4 92us bug).
        asm volatile("s_waitcnt vmcnt(0)" ::: "memory");
        unsigned int last = 0u;
        unsigned int g = (unsigned)(k & (NGRP - 1));      // spread level-1 lines
        unsigned int t1 = atomicAdd(&tickets[g * LINE_U32], 1u);
        if (t1 == (unsigned)(GRPSZ - 1)) {                // last in group (of 64)
            unsigned int t2 = atomicAdd(&tickets[NGRP * LINE_U32], 1u);
            last = (t2 == (unsigned)(NGRP - 1));          // last of 32 groups
        }
        s_islast = last;
    }
    __syncthreads();

    if (s_islast) {
        // ---------- in-kernel finalize (last block only) ----------
        // sc1 read-through loads: bypass stale L1/L2, read the coherent point.
        float c = 0.0f, wh = 0.0f, of = 0.0f, af = 0.0f;
        for (int i = t; i < NBLK; i += 256) {
            const float* wp = ws + 4 * i;
            c  += __hip_atomic_load(wp + 0, __ATOMIC_RELAXED, __HIP_MEMORY_SCOPE_AGENT);
            wh += __hip_atomic_load(wp + 1, __ATOMIC_RELAXED, __HIP_MEMORY_SCOPE_AGENT);
            of += __hip_atomic_load(wp + 2, __ATOMIC_RELAXED, __HIP_MEMORY_SCOPE_AGENT);
            af += __hip_atomic_load(wp + 3, __ATOMIC_RELAXED, __HIP_MEMORY_SCOPE_AGENT);
        }
        float fc = block_reduce_add(c, sred);  __syncthreads();
        float fw = block_reduce_add(wh, sred); __syncthreads();
        float fo = block_reduce_add(of, sred); __syncthreads();
        float fa = block_reduce_add(af, sred);
        if (t == 0) {
            float a = fmaxf(1.0f, fa);
            out[0] = fc / (a + EPS32)
                   + 0.1f * fw / (a * 2.0f + EPS32)
                   + fo / (a * 2.0f + EPS32);
        }
    }
}

extern "C" void kernel_launch(void* const* d_in, const int* in_sizes, int n_in,
                              void* d_out, int out_size, void* d_ws, size_t ws_size,
                              hipStream_t stream) {
    const float* cp     = (const float*)d_in[0];   // center_pred (16,80,128,128)
    const float* whp    = (const float*)d_in[1];   // wh_pred     (16,2,128,128)
    const float* ofp    = (const float*)d_in[2];   // offset_pred (16,2,128,128)
    const float* boxes  = (const float*)d_in[3];   // (16,64,4)
    const int*   labels = (const int*)d_in[4];     // (16,64)
    float* ws = (float*)d_ws;                      // 4*NBLK float partials (32 KB)
    unsigned int* tickets = (unsigned int*)((char*)d_ws + 4 * NBLK * sizeof(float));

    // Workspace is re-poisoned each iteration -> tickets MUST be zeroed.
    // One stream-ordered memset over the 33 counter lines (4.2 KB), ~1 us.
    hipMemsetAsync(tickets, 0, (NGRP + 1) * LINE_U32 * sizeof(unsigned int), stream);
    fused_kernel<<<NBLK, 256, 0, stream>>>(cp, whp, ofp, boxes, labels, ws,
                                           tickets, (float*)d_out);
}

// Round 6
// 130.814 us; speedup vs baseline: 1.4456x; 1.0309x over previous
//
#include <hip/hip_runtime.h>
#include <math.h>

#define EPS32 1.1920929e-07f

// FINAL (reverted-to-best) structure, per R0-R5 evidence:
//  - R1: cooperative grid.sync() => 114 us kernel (XCD-spin). Falsified.
//  - R3: last-block + __threadfence => 92 us (per-block buffer_wbl2 L2
//        writeback; NOT atomic line contention - R4 proved spreading lines
//        changes nothing). Falsified.
//  - R5: fence-free last-block (sc0/sc1 coherent stores + ticket) => kernel
//        fast again but total 134.9 vs 131.7: memset dispatch + coherent
//        read-through tail cost more than the finalize launch they replaced.
//        Falsified.
//  => The plain two-kernel pipeline is the measured optimum. Remaining window:
//     2x ~52 us harness workspace re-poison fills (untouchable) + ~13.3 us
//     mandatory 84 MB read of center_pred (HBM/L3 roofline) + ~3 us finalize
//     + ~5 us launch overhead.

constexpr int B = 16, C = 80, H = 128, W = 128, NBOX = 64;
constexpr int NCORR = B * NBOX;        // 1024 correction-carrying blocks
constexpr int NBLK  = 2048;            // all blocks stream; 8 blocks/CU, one round
constexpr int NTOT  = B * C * H * W;   // 20,971,520
constexpr int NV4   = NTOT / 4;        // 5,242,880 float4s
constexpr int SSTRIDE = NBLK * 256;    // 524,288 -> exactly 10 float4 iters/thread
constexpr int SITER = NV4 / SSTRIDE;   // 10
static_assert(SITER * SSTRIDE == NV4, "streaming must tile exactly");

__device__ __forceinline__ float f0_term(float p) {
    // ct == 0 branch of the focal loss: -log(1-p+1e-12) * p^2
    return -__logf(1.0f - p + 1e-12f) * p * p;
}

// Block-wide sum; result valid on thread 0 only. Contains one __syncthreads.
__device__ __forceinline__ float block_reduce_add(float v, float* sred) {
    #pragma unroll
    for (int off = 32; off > 0; off >>= 1)
        v += __shfl_down(v, off, 64);
    int lane = threadIdx.x & 63;
    int wid  = threadIdx.x >> 6;
    if (lane == 0) sred[wid] = v;
    __syncthreads();
    if (threadIdx.x == 0) {
        float s = sred[0];
        #pragma unroll
        for (int i = 1; i < 4; ++i) s += sred[i];
        return s;
    }
    return 0.0f;
}

// Each block writes one float4 partial {center, wh, offset, af} to ws4[blockIdx.x].
// Blocks 0..NCORR-1 additionally own box (b = k>>6, n = k&63)'s sparse correction.
// All blocks stream a 1/2048 slice of center_pred (balanced: 10 float4s/thread).
__global__ __launch_bounds__(256) void fused_kernel(
    const float* __restrict__ cp, const float* __restrict__ whp,
    const float* __restrict__ ofp, const float* __restrict__ boxes,
    const int* __restrict__ labels, float4* __restrict__ ws4)
{
    __shared__ float sred[4];
    __shared__ int   scx[NBOX], scy[NBOX], sre[NBOX], slab[NBOX];
    __shared__ float sinv[NBOX];
    __shared__ unsigned long long cand_mask;   // same-batch same-label boxes
    __shared__ float s_woa[3];                 // {wh, offset, af} from thread n
    const int t = threadIdx.x;
    const int k = blockIdx.x;
    const bool has_box = (k < NCORR);
    const int b = (k >> 6) & (B - 1);
    const int n = k & 63;

    if (has_box) {
        // ---------- box setup (wave 0) ----------
        if (t < NBOX) {
            const float* bx = boxes + ((b * NBOX + t) << 2);
            float x1 = bx[0], y1 = bx[1], x2 = bx[2], y2 = bx[3];
            // w_ratio = h_ratio = 128/512 = 0.25 (exact power-of-2 scalings)
            float cx = (x1 + x2) * 0.25f * 0.5f;
            float cy = (y1 + y2) * 0.25f * 0.5f;
            int cxi = (int)floorf(cx);
            int cyi = (int)floorf(cy);
            float sw = (x2 - x1) * 0.25f;
            float sh = (y2 - y1) * 0.25f;
            // gaussian radius, min_overlap = 0.3 (h = sh, w = sw)
            float h = sh, w = sw;
            float b1 = h + w;
            float c1 = w * h * 0.7f / 1.3f;
            float r1 = (b1 - sqrtf(b1 * b1 - 4.0f * c1)) * 0.5f;
            float b2 = 2.0f * (h + w);
            float c2 = 0.7f * w * h;
            float r2 = (b2 - sqrtf(b2 * b2 - 16.0f * c2)) * 0.125f;
            float b3 = -0.6f * (h + w);
            float c3 = -0.7f * w * h;
            float r3 = (b3 + sqrtf(b3 * b3 - 4.8f * c3)) / 2.4f;
            float r = fminf(fminf(r1, r2), r3);
            int rad = (int)fmaxf(0.0f, floorf(r));
            float d = (float)(2 * rad + 1);
            float sigma2 = 2.0f * d / 6.0f * (d / 6.0f);
            scx[t] = cxi; scy[t] = cyi;
            sre[t] = rad < 16 ? rad : 16;     // window clamp (reference grid is +-16)
            slab[t] = labels[b * NBOX + t];
            sinv[t] = 1.0f / sigma2;
            if (t == 0) { s_woa[0] = 0.0f; s_woa[1] = 0.0f; s_woa[2] = 0.0f; }
            // keep per-thread box values for the t==n writes below
            float ox = cx - (float)cxi, oy = cy - (float)cyi;
            __syncthreads();
            // ---------- wave-0 ballots replace serial thread-0 loops ----------
            const int cxn = scx[n], cyn = scy[n], labn = slab[n];
            bool same_cell = (scx[t] == cxn) && (scy[t] == cyn);
            // wh/offset scatter-set => last write (max index) wins per (cyi,cxi)
            unsigned long long clash = __ballot(same_cell && (t > n));
            // af counts distinct (label, cyi, cxi) => first occurrence
            unsigned long long firstm = __ballot(same_cell && (slab[t] == labn) && (t < n));
            // candidate set for the gaussian max: same-batch same-label boxes
            unsigned long long cand = __ballot(slab[t] == labn);
            if (t == n) {
                cand_mask = cand;
                if (clash == 0ULL) {
                    int i0 = ((b * 2 + 0) * H + cyn) * W + cxn;
                    int i1 = ((b * 2 + 1) * H + cyn) * W + cxn;
                    s_woa[0] = fabsf(whp[i0] - sw) + fabsf(whp[i1] - sh);
                    s_woa[1] = fabsf(ofp[i0] - ox) + fabsf(ofp[i1] - oy);
                }
                if (firstm == 0ULL) s_woa[2] = 1.0f;
            }
        } else {
            __syncthreads();   // matches the wave-0 barrier above
        }
    }

    // ---------- dense streaming slice (all blocks): 10 float4s/thread ----------
    const float4* cp4 = (const float4*)cp;
    const int base = k * 256 + t;
    float s0 = 0.0f, s1 = 0.0f;
    #pragma unroll 1
    for (int j = 0; j < SITER; j += 2) {
        float4 a  = cp4[base + (j + 0) * SSTRIDE];
        float4 bb = cp4[base + (j + 1) * SSTRIDE];
        s0 += f0_term(a.x) + f0_term(a.y) + f0_term(a.z) + f0_term(a.w);
        s1 += f0_term(bb.x) + f0_term(bb.y) + f0_term(bb.z) + f0_term(bb.w);
    }
    float center = s0 + s1;

    if (has_box) {
        __syncthreads();   // cand_mask / box LDS visible to all 4 waves

        // ---------- sparse correction: this block's box window ----------
        const int c   = slab[n];
        const int R   = sre[n];
        const int Wd  = 2 * R + 1;
        const int cells = Wd * Wd;
        const int cx0 = scx[n], cy0 = scy[n];
        const unsigned long long cmask = cand_mask;
        float corr = 0.0f;
        for (int cell = t; cell < cells; cell += 256) {
            int dy = cell / Wd - R;
            int dx = cell - (dy + R) * Wd - R;
            int y = cy0 + dy, x = cx0 + dx;
            if ((unsigned)y >= (unsigned)H || (unsigned)x >= (unsigned)W) continue;
            // ct = max gaussian over covering same-label boxes; owner = min index
            int minm = NBOX;
            float ct = 0.0f;
            unsigned long long mm = cmask;
            while (mm) {
                int m = __ffsll(mm) - 1;
                mm &= mm - 1;
                int ddx = x - scx[m], ddy = y - scy[m];
                int re = sre[m];
                if (ddx > re || ddx < -re || ddy > re || ddy < -re) continue;
                if (m < minm) minm = m;
                float d2 = (float)(ddx * ddx + ddy * ddy);
                float kv = (d2 == 0.0f) ? 1.0f : __expf(-d2 * sinv[m]);
                if (kv < EPS32) kv = 0.0f;          // reference EPS cut
                ct = fmaxf(ct, kv);
            }
            if (minm == n) {                         // this block owns the cell
                float p = cp[((b * C + c) * H + y) * W + x];
                float lt = __logf(1.0f - p + 1e-12f);
                float omc = 1.0f - ct;
                float w2 = omc * omc;
                float w4 = w2 * w2;
                // f(p,ct) - f0(p): neg-weight delta + pos term at exact centers
                float val = -lt * p * p * (w4 - 1.0f);
                if (ct == 1.0f) {
                    float q = 1.0f - p;
                    val += -__logf(p + 1e-12f) * q * q;
                }
                corr += val;
            }
        }
        center += corr;
    }

    float cs = block_reduce_add(center, sred);   // contains a __syncthreads
    if (t == 0) {
        float4 out;
        out.x = cs;
        if (has_box) { out.y = s_woa[0]; out.z = s_woa[1]; out.w = s_woa[2]; }
        else         { out.y = 0.0f;     out.z = 0.0f;     out.w = 0.0f;     }
        ws4[k] = out;
    }
}

__global__ __launch_bounds__(256) void finalize_kernel(
    const float4* __restrict__ ws4, float* __restrict__ out)
{
    __shared__ float sred[4];
    float c = 0.0f, wh = 0.0f, of = 0.0f, af = 0.0f;
    for (int i = threadIdx.x; i < NBLK; i += 256) {
        float4 v = ws4[i];
        c += v.x; wh += v.y; of += v.z; af += v.w;
    }
    float cs = block_reduce_add(c, sred);  __syncthreads();
    float ws = block_reduce_add(wh, sred); __syncthreads();
    float os = block_reduce_add(of, sred); __syncthreads();
    float as = block_reduce_add(af, sred);
    if (threadIdx.x == 0) {
        float a = fmaxf(1.0f, as);
        out[0] = cs / (a + EPS32)
               + 0.1f * ws / (a * 2.0f + EPS32)
               + os / (a * 2.0f + EPS32);
    }
}

extern "C" void kernel_launch(void* const* d_in, const int* in_sizes, int n_in,
                              void* d_out, int out_size, void* d_ws, size_t ws_size,
                              hipStream_t stream) {
    const float* cp     = (const float*)d_in[0];   // center_pred (16,80,128,128)
    const float* whp    = (const float*)d_in[1];   // wh_pred     (16,2,128,128)
    const float* ofp    = (const float*)d_in[2];   // offset_pred (16,2,128,128)
    const float* boxes  = (const float*)d_in[3];   // (16,64,4)
    const int*   labels = (const int*)d_in[4];     // (16,64)
    float4* ws4 = (float4*)d_ws;                   // NBLK float4 partials (32 KB)

    fused_kernel<<<NBLK, 256, 0, stream>>>(cp, whp, ofp, boxes, labels, ws4);
    finalize_kernel<<<1, 256, 0, stream>>>(ws4, (float*)d_out);
}